// Round 1
// baseline (6185.628 us; speedup 1.0000x reference)
//
#include <hip/hip_runtime.h>
#include <math.h>

#define BATCH 128
#define NF 49
#define EDIM 2048
#define EMBD 512
#define DDIM 512
#define VOC 12000
#define TT 21
#define G4 2048   // 4*D

// ---------------- generic f32 GEMM: C[m][n] = sum_k A[m][k]*W[n][k] (+bias[n]) (+add1[m][n]) (+add2[m][n]) ----------------
#define BM 64
#define BN 64
#define BK 16

__global__ __launch_bounds__(256) void gemm_f32(
    const float* __restrict__ A, int lda,
    const float* __restrict__ W, int ldw,
    float* __restrict__ C, int ldc,
    const float* __restrict__ bias,
    const float* __restrict__ add1, int ldadd1,
    const float* __restrict__ add2, int ldadd2,
    int M, int Nn, int K)
{
    __shared__ float As[BK][BM + 1];
    __shared__ float Ws[BK][BN + 1];
    const int bm = blockIdx.y * BM;
    const int bn = blockIdx.x * BN;
    const int tx = threadIdx.x;   // 0..15
    const int ty = threadIdx.y;   // 0..15
    const int tid = ty * 16 + tx;

    const int lm = tid >> 2;        // 0..63
    const int lk = (tid & 3) * 4;   // 0,4,8,12

    float acc[4][4] = {};

    for (int k0 = 0; k0 < K; k0 += BK) {
        {
            int row = bm + lm;
            float4 v = make_float4(0.f, 0.f, 0.f, 0.f);
            if (row < M) v = *(const float4*)(A + (size_t)row * lda + k0 + lk);
            As[lk + 0][lm] = v.x; As[lk + 1][lm] = v.y;
            As[lk + 2][lm] = v.z; As[lk + 3][lm] = v.w;
        }
        {
            int row = bn + lm;
            float4 v = make_float4(0.f, 0.f, 0.f, 0.f);
            if (row < Nn) v = *(const float4*)(W + (size_t)row * ldw + k0 + lk);
            Ws[lk + 0][lm] = v.x; Ws[lk + 1][lm] = v.y;
            Ws[lk + 2][lm] = v.z; Ws[lk + 3][lm] = v.w;
        }
        __syncthreads();
        #pragma unroll
        for (int kk = 0; kk < BK; ++kk) {
            float a0 = As[kk][ty * 4 + 0];
            float a1 = As[kk][ty * 4 + 1];
            float a2 = As[kk][ty * 4 + 2];
            float a3 = As[kk][ty * 4 + 3];
            float b0 = Ws[kk][tx * 4 + 0];
            float b1 = Ws[kk][tx * 4 + 1];
            float b2 = Ws[kk][tx * 4 + 2];
            float b3 = Ws[kk][tx * 4 + 3];
            acc[0][0] += a0 * b0; acc[0][1] += a0 * b1; acc[0][2] += a0 * b2; acc[0][3] += a0 * b3;
            acc[1][0] += a1 * b0; acc[1][1] += a1 * b1; acc[1][2] += a1 * b2; acc[1][3] += a1 * b3;
            acc[2][0] += a2 * b0; acc[2][1] += a2 * b1; acc[2][2] += a2 * b2; acc[2][3] += a2 * b3;
            acc[3][0] += a3 * b0; acc[3][1] += a3 * b1; acc[3][2] += a3 * b2; acc[3][3] += a3 * b3;
        }
        __syncthreads();
    }

    #pragma unroll
    for (int i = 0; i < 4; ++i) {
        int row = bm + ty * 4 + i;
        if (row >= M) continue;
        #pragma unroll
        for (int j = 0; j < 4; ++j) {
            int col = bn + tx * 4 + j;
            if (col >= Nn) continue;
            float v = acc[i][j];
            if (bias) v += bias[col];
            if (add1) v += add1[(size_t)row * ldadd1 + col];
            if (add2) v += add2[(size_t)row * ldadd2 + col];
            C[(size_t)row * ldc + col] = v;
        }
    }
}

// ---------------- small helper kernels ----------------

__global__ __launch_bounds__(256) void mean_feat_kernel(const float* __restrict__ features,
                                                        float* __restrict__ mean_f)
{
    int idx = blockIdx.x * 256 + threadIdx.x;       // B*E
    int b = idx >> 11, e = idx & 2047;
    float s = 0.f;
    for (int n = 0; n < NF; ++n)
        s += features[((size_t)(b * NF + n)) * EDIM + e];
    mean_f[idx] = s * (1.0f / NF);
}

__global__ __launch_bounds__(256) void gather_embed_kernel(const int* __restrict__ captions,
                                                           const float* __restrict__ embedding,
                                                           float* __restrict__ embeds)
{
    int idx = blockIdx.x * 256 + threadIdx.x;       // B*T*EMB
    int m = idx >> 9;                               // b*T + t
    int j = idx & 511;
    int b = m / TT, t = m - b * TT;
    int word = captions[b * (TT + 1) + t];
    embeds[idx] = embedding[(size_t)word * EMBD + j];
}

__global__ __launch_bounds__(256) void bias_sum_kernel(const float* __restrict__ b_ih,
                                                       const float* __restrict__ b_hh,
                                                       float* __restrict__ bsum)
{
    int j = blockIdx.x * 256 + threadIdx.x;
    if (j < G4) bsum[j] = b_ih[j] + b_hh[j];
}

// ---------------- per-step attention: scores + softmax + gate_ctx ----------------

__global__ __launch_bounds__(256) void attend_kernel(
    const float* __restrict__ f_proj,   // B*NF*D
    const float* __restrict__ h_proj,   // B*D
    const float* __restrict__ Va_w,     // D
    const float* __restrict__ Va_b,     // 1
    const float* __restrict__ F_ih,     // B*NF*G4
    float* __restrict__ gate_ctx,       // B*G4
    float* __restrict__ out_w,          // B*T*NF
    int t)
{
    const int b = blockIdx.x;
    __shared__ float s[64];
    const int tid = threadIdx.x;
    const int wave = tid >> 6;
    const int lane = tid & 63;

    const float* hp = h_proj + (size_t)b * DDIM;
    for (int n = wave; n < NF; n += 4) {
        const float* fp = f_proj + ((size_t)(b * NF + n)) * DDIM;
        float sum = 0.f;
        for (int d = lane; d < DDIM; d += 64)
            sum += Va_w[d] * tanhf(fp[d] + hp[d]);
        for (int off = 32; off; off >>= 1) sum += __shfl_down(sum, off);
        if (lane == 0) s[n] = sum + Va_b[0];
    }
    __syncthreads();
    if (tid < 64) {
        float v = (lane < NF) ? s[lane] : -1e30f;
        float mx = v;
        for (int off = 32; off; off >>= 1) mx = fmaxf(mx, __shfl_xor(mx, off));
        float e = (lane < NF) ? expf(v - mx) : 0.f;
        float sm = e;
        for (int off = 32; off; off >>= 1) sm += __shfl_xor(sm, off);
        float p = e / sm;
        if (lane < NF) {
            s[lane] = p;
            out_w[((size_t)b * TT + t) * NF + lane] = p;
        }
    }
    __syncthreads();
    for (int j = tid; j < G4; j += 256) {
        float acc = 0.f;
        const float* fi = F_ih + (size_t)b * NF * G4 + j;
        #pragma unroll 7
        for (int n = 0; n < NF; ++n)
            acc += s[n] * fi[(size_t)n * G4];
        gate_ctx[(size_t)b * G4 + j] = acc;
    }
}

// ---------------- LSTM cell elementwise ----------------

__device__ __forceinline__ float sigmoidf(float x) { return 1.f / (1.f + expf(-x)); }

__global__ __launch_bounds__(256) void lstm_cell_kernel(const float* __restrict__ gates,
                                                        float* __restrict__ h,
                                                        float* __restrict__ c,
                                                        float* __restrict__ H_all,
                                                        int t)
{
    int idx = blockIdx.x * 256 + threadIdx.x;   // B*D
    int b = idx >> 9, j = idx & 511;
    const float* g = gates + (size_t)b * G4;
    float iv = sigmoidf(g[j]);
    float fv = sigmoidf(g[j + DDIM]);
    float gv = tanhf(g[j + 2 * DDIM]);
    float ov = sigmoidf(g[j + 3 * DDIM]);
    float c2 = fv * c[idx] + iv * gv;
    float h2 = ov * tanhf(c2);
    c[idx] = c2;
    h[idx] = h2;
    H_all[((size_t)b * TT + t) * DDIM + j] = h2;
}

// ---------------- host side ----------------

static void launch_gemm(hipStream_t stream,
                        const float* A, int lda, const float* W, int ldw,
                        float* C, int ldc, const float* bias,
                        const float* add1, int ldadd1,
                        const float* add2, int ldadd2,
                        int M, int Nn, int K)
{
    dim3 grid((Nn + BN - 1) / BN, (M + BM - 1) / BM);
    dim3 block(16, 16);
    hipLaunchKernelGGL(gemm_f32, grid, block, 0, stream,
                       A, lda, W, ldw, C, ldc, bias, add1, ldadd1, add2, ldadd2, M, Nn, K);
}

extern "C" void kernel_launch(void* const* d_in, const int* in_sizes, int n_in,
                              void* d_out, int out_size, void* d_ws, size_t ws_size,
                              hipStream_t stream)
{
    const float* features = (const float*)d_in[0];
    const int*   captions = (const int*)d_in[1];
    const float* embedding= (const float*)d_in[2];
    const float* Wa_w = (const float*)d_in[3];
    const float* Wa_b = (const float*)d_in[4];
    const float* Ua_w = (const float*)d_in[5];
    const float* Ua_b = (const float*)d_in[6];
    const float* Va_w = (const float*)d_in[7];
    const float* Va_b = (const float*)d_in[8];
    const float* W_ih = (const float*)d_in[9];
    const float* W_hh = (const float*)d_in[10];
    const float* b_ih = (const float*)d_in[11];
    const float* b_hh = (const float*)d_in[12];
    const float* ih_w = (const float*)d_in[13];
    const float* ih_b = (const float*)d_in[14];
    const float* ic_w = (const float*)d_in[15];
    const float* ic_b = (const float*)d_in[16];
    const float* fc_w = (const float*)d_in[17];
    const float* fc_b = (const float*)d_in[18];

    float* out_w = (float*)d_out;                          // B*T*NF
    float* out_p = out_w + (size_t)BATCH * TT * NF;        // B*T*V

    float* ws = (float*)d_ws;
    float* f_proj   = ws;                      // B*NF*D      = 3,211,264
    float* F_ih     = f_proj + 3211264;        // B*NF*G4     = 12,845,056
    float* E_ih     = F_ih + 12845056;         // B*T*G4      = 5,505,024
    float* embeds   = E_ih + 5505024;          // B*T*EMB     = 1,376,256
    float* H_all    = embeds + 1376256;        // B*T*D       = 1,376,256
    float* mean_f   = H_all + 1376256;         // B*E         = 262,144
    float* h        = mean_f + 262144;         // B*D         = 65,536
    float* c        = h + 65536;               // B*D         = 65,536
    float* h_proj   = c + 65536;               // B*D         = 65,536
    float* gate_ctx = h_proj + 65536;          // B*G4        = 262,144
    float* gates    = gate_ctx + 262144;       // B*G4        = 262,144
    float* bsum     = gates + 262144;          // G4          = 2,048

    // ---- precompute (parallel, out of the time loop) ----
    hipLaunchKernelGGL(mean_feat_kernel, dim3(BATCH * EDIM / 256), dim3(256), 0, stream,
                       features, mean_f);
    // h0 = mean_f @ ih_w.T + ih_b ; c0 = mean_f @ ic_w.T + ic_b
    launch_gemm(stream, mean_f, EDIM, ih_w, EDIM, h, DDIM, ih_b, nullptr, 0, nullptr, 0,
                BATCH, DDIM, EDIM);
    launch_gemm(stream, mean_f, EDIM, ic_w, EDIM, c, DDIM, ic_b, nullptr, 0, nullptr, 0,
                BATCH, DDIM, EDIM);
    hipLaunchKernelGGL(gather_embed_kernel, dim3(BATCH * TT * EMBD / 256), dim3(256), 0, stream,
                       captions, embedding, embeds);
    hipLaunchKernelGGL(bias_sum_kernel, dim3(G4 / 256), dim3(256), 0, stream, b_ih, b_hh, bsum);
    // f_proj = features @ Wa_w.T + Wa_b
    launch_gemm(stream, features, EDIM, Wa_w, EDIM, f_proj, DDIM, Wa_b, nullptr, 0, nullptr, 0,
                BATCH * NF, DDIM, EDIM);
    // F_ih = features @ W_ih[:, :E].T
    launch_gemm(stream, features, EDIM, W_ih, EDIM + EMBD, F_ih, G4, nullptr, nullptr, 0, nullptr, 0,
                BATCH * NF, G4, EDIM);
    // E_ih = embeds @ W_ih[:, E:].T + (b_ih + b_hh)
    launch_gemm(stream, embeds, EMBD, W_ih + EDIM, EDIM + EMBD, E_ih, G4, bsum, nullptr, 0, nullptr, 0,
                BATCH * TT, G4, EMBD);

    // ---- sequential time loop ----
    for (int t = 0; t < TT; ++t) {
        // h_proj = h @ Ua_w.T + Ua_b
        launch_gemm(stream, h, DDIM, Ua_w, DDIM, h_proj, DDIM, Ua_b, nullptr, 0, nullptr, 0,
                    BATCH, DDIM, DDIM);
        hipLaunchKernelGGL(attend_kernel, dim3(BATCH), dim3(256), 0, stream,
                           f_proj, h_proj, Va_w, Va_b, F_ih, gate_ctx, out_w, t);
        // gates = gate_ctx + E_ih[:,t,:] + h @ W_hh.T
        launch_gemm(stream, h, DDIM, W_hh, DDIM, gates, G4, nullptr,
                    gate_ctx, G4, E_ih + (size_t)t * G4, TT * G4,
                    BATCH, G4, DDIM);
        hipLaunchKernelGGL(lstm_cell_kernel, dim3(BATCH * DDIM / 256), dim3(256), 0, stream,
                           gates, h, c, H_all, t);
    }

    // ---- preds = H_all @ fc_w.T + fc_b ----
    launch_gemm(stream, H_all, DDIM, fc_w, DDIM, out_p, VOC, fc_b, nullptr, 0, nullptr, 0,
                BATCH * TT, VOC, DDIM);
}

// Round 4
// 3391.888 us; speedup vs baseline: 1.8237x; 1.8237x over previous
//
#include <hip/hip_runtime.h>
#include <math.h>

#define BATCH 128
#define NF 49
#define EDIM 2048
#define EMBD 512
#define DDIM 512
#define VOC 12000
#define TT 21
#define G4 2048   // 4*D
#define UWN 2560  // 512 + 2048

typedef __bf16 bf16x8 __attribute__((ext_vector_type(8)));
typedef float f32x4 __attribute__((ext_vector_type(4)));
typedef unsigned short ushortx8 __attribute__((ext_vector_type(8)));

__device__ __forceinline__ unsigned short bf16_rne(float x) {
    union { float f; unsigned u; } v; v.f = x;
    unsigned r = v.u + 0x7fffu + ((v.u >> 16) & 1u);
    return (unsigned short)(r >> 16);
}
__device__ __forceinline__ float bf16_to_f(unsigned short h) {
    union { unsigned u; float f; } v; v.u = ((unsigned)h) << 16;
    return v.f;
}
__device__ __forceinline__ float sigmoidf(float x) { return 1.f / (1.f + expf(-x)); }

// =======================================================================
// bf16x3 split-precision MFMA GEMM: C[m][n] = sum_k A[m][k]*W[n][k] + bias[n]
// A: f32 (M x K, lda), W: f32 (Nn x K, ldw). M must be a multiple of 128.
// Nn may be ragged (W-row reads and C-writes are guarded). K multiple of 32.
// 128x128 tile, 4 waves (each 64x64), reg-staged f32->bf16 hi/lo split into
// XOR-swizzled LDS, 3 MFMAs per fragment pair (hi*hi + hi*lo + lo*hi).
// =======================================================================
__global__ __launch_bounds__(256) void gemm_bf16x3(
    const float* __restrict__ A, int lda,
    const float* __restrict__ W, int ldw,
    float* __restrict__ C, int ldc,
    const float* __restrict__ bias,
    int Nn, int K)
{
    __shared__ unsigned short Ah[128 * 32];
    __shared__ unsigned short Al[128 * 32];
    __shared__ unsigned short Wh[128 * 32];
    __shared__ unsigned short Wl[128 * 32];

    // bijective XCD-aware block swizzle (m204)
    const int nbx = gridDim.x;
    const int nwg = nbx * gridDim.y;
    const int orig = blockIdx.y * nbx + blockIdx.x;
    const int q = nwg >> 3, r = nwg & 7;
    const int xcd = orig & 7, pos = orig >> 3;
    const int swz = (xcd < r ? xcd * (q + 1) : r * (q + 1) + (xcd - r) * q) + pos;
    const int by = swz / nbx, bx = swz - by * nbx;

    const int bm = by * 128;
    const int bn = bx * 128;
    const int tid = threadIdx.x;
    const int wid = tid >> 6;
    const int lane = tid & 63;
    const int wr = (wid >> 1) * 64;   // wave row offset in tile
    const int wc = (wid & 1) * 64;    // wave col offset in tile

    const int srow = tid >> 1;          // staging row 0..127
    const int scol = (tid & 1) * 16;    // staging col 0 or 16 (f32 elements)
    const int slotbase = scol >> 3;     // 16B-slot index base (0 or 2)

    const int fr = lane & 15;
    const int ksl = lane >> 4;          // k-slot 0..3 (k = ksl*8)

    f32x4 acc[4][4] = {};

    const float* asrc0 = A + (size_t)(bm + srow) * lda + scol;
    const int wrow = bn + srow;
    const bool wok = wrow < Nn;
    const float* wsrc0 = W + (size_t)wrow * ldw + scol;

    for (int k0 = 0; k0 < K; k0 += 32) {
        // ---- stage A ----
        {
            ushortx8 h0v, h1v, l0v, l1v;
            const float* src = asrc0 + k0;
            #pragma unroll
            for (int v = 0; v < 4; ++v) {
                float4 f = *(const float4*)(src + 4 * v);
                #define SPL(val, qq) { unsigned short hh = bf16_rne(val); \
                    unsigned short ll = bf16_rne((val) - bf16_to_f(hh)); \
                    if ((qq) < 8) { h0v[(qq)] = hh; l0v[(qq)] = ll; } \
                    else { h1v[(qq)-8] = hh; l1v[(qq)-8] = ll; } }
                SPL(f.x, 4 * v + 0) SPL(f.y, 4 * v + 1)
                SPL(f.z, 4 * v + 2) SPL(f.w, 4 * v + 3)
            }
            int sl0 = ((slotbase + 0) ^ (srow & 3)) * 8;
            int sl1 = ((slotbase + 1) ^ (srow & 3)) * 8;
            *(ushortx8*)&Ah[srow * 32 + sl0] = h0v;
            *(ushortx8*)&Ah[srow * 32 + sl1] = h1v;
            *(ushortx8*)&Al[srow * 32 + sl0] = l0v;
            *(ushortx8*)&Al[srow * 32 + sl1] = l1v;
        }
        // ---- stage W (guarded) ----
        {
            ushortx8 h0v, h1v, l0v, l1v;
            const float* src = wsrc0 + k0;
            #pragma unroll
            for (int v = 0; v < 4; ++v) {
                float4 f = wok ? *(const float4*)(src + 4 * v)
                               : make_float4(0.f, 0.f, 0.f, 0.f);
                SPL(f.x, 4 * v + 0) SPL(f.y, 4 * v + 1)
                SPL(f.z, 4 * v + 2) SPL(f.w, 4 * v + 3)
                #undef SPL
            }
            int sl0 = ((slotbase + 0) ^ (srow & 3)) * 8;
            int sl1 = ((slotbase + 1) ^ (srow & 3)) * 8;
            *(ushortx8*)&Wh[srow * 32 + sl0] = h0v;
            *(ushortx8*)&Wh[srow * 32 + sl1] = h1v;
            *(ushortx8*)&Wl[srow * 32 + sl0] = l0v;
            *(ushortx8*)&Wl[srow * 32 + sl1] = l1v;
        }
        __syncthreads();

        bf16x8 av_h[4], av_l[4], wv_h[4], wv_l[4];
        #pragma unroll
        for (int m = 0; m < 4; ++m) {
            int ar = wr + m * 16 + fr;
            int sl = (ksl ^ (ar & 3)) * 8;
            av_h[m] = *(const bf16x8*)&Ah[ar * 32 + sl];
            av_l[m] = *(const bf16x8*)&Al[ar * 32 + sl];
        }
        #pragma unroll
        for (int n = 0; n < 4; ++n) {
            int wrw = wc + n * 16 + fr;
            int sl = (ksl ^ (wrw & 3)) * 8;
            wv_h[n] = *(const bf16x8*)&Wh[wrw * 32 + sl];
            wv_l[n] = *(const bf16x8*)&Wl[wrw * 32 + sl];
        }
        #pragma unroll
        for (int m = 0; m < 4; ++m)
            #pragma unroll
            for (int n = 0; n < 4; ++n) {
                acc[m][n] = __builtin_amdgcn_mfma_f32_16x16x32_bf16(av_h[m], wv_h[n], acc[m][n], 0, 0, 0);
                acc[m][n] = __builtin_amdgcn_mfma_f32_16x16x32_bf16(av_h[m], wv_l[n], acc[m][n], 0, 0, 0);
                acc[m][n] = __builtin_amdgcn_mfma_f32_16x16x32_bf16(av_l[m], wv_h[n], acc[m][n], 0, 0, 0);
            }
        __syncthreads();
    }

    // ---- epilogue: C/D layout col=lane&15, row=(lane>>4)*4+reg ----
    #pragma unroll
    for (int n = 0; n < 4; ++n) {
        int col = bn + wc + n * 16 + (lane & 15);
        if (col >= Nn) continue;
        float bv = bias ? bias[col] : 0.f;
        #pragma unroll
        for (int m = 0; m < 4; ++m) {
            int row0 = bm + wr + m * 16 + (lane >> 4) * 4;
            #pragma unroll
            for (int rg = 0; rg < 4; ++rg)
                C[(size_t)(row0 + rg) * ldc + col] = acc[m][n][rg] + bv;
        }
    }
}

// =======================================================================
// f32 vector GEMM (for the small M=128 ops): C = A*W^T + bias
// =======================================================================
#define BM 64
#define BN 64
#define BK 16

__global__ __launch_bounds__(256) void gemm_f32(
    const float* __restrict__ A, int lda,
    const float* __restrict__ W, int ldw,
    float* __restrict__ C, int ldc,
    const float* __restrict__ bias,
    int M, int Nn, int K)
{
    __shared__ float As[BK][BM + 1];
    __shared__ float Ws[BK][BN + 1];
    const int bm = blockIdx.y * BM;
    const int bn = blockIdx.x * BN;
    const int tx = threadIdx.x;
    const int ty = threadIdx.y;
    const int tid = ty * 16 + tx;
    const int lm = tid >> 2;
    const int lk = (tid & 3) * 4;

    float acc[4][4] = {};

    for (int k0 = 0; k0 < K; k0 += BK) {
        {
            int row = bm + lm;
            float4 v = make_float4(0.f, 0.f, 0.f, 0.f);
            if (row < M) v = *(const float4*)(A + (size_t)row * lda + k0 + lk);
            As[lk + 0][lm] = v.x; As[lk + 1][lm] = v.y;
            As[lk + 2][lm] = v.z; As[lk + 3][lm] = v.w;
        }
        {
            int row = bn + lm;
            float4 v = make_float4(0.f, 0.f, 0.f, 0.f);
            if (row < Nn) v = *(const float4*)(W + (size_t)row * ldw + k0 + lk);
            Ws[lk + 0][lm] = v.x; Ws[lk + 1][lm] = v.y;
            Ws[lk + 2][lm] = v.z; Ws[lk + 3][lm] = v.w;
        }
        __syncthreads();
        #pragma unroll
        for (int kk = 0; kk < BK; ++kk) {
            float a0 = As[kk][ty * 4 + 0];
            float a1 = As[kk][ty * 4 + 1];
            float a2 = As[kk][ty * 4 + 2];
            float a3 = As[kk][ty * 4 + 3];
            float b0 = Ws[kk][tx * 4 + 0];
            float b1 = Ws[kk][tx * 4 + 1];
            float b2 = Ws[kk][tx * 4 + 2];
            float b3 = Ws[kk][tx * 4 + 3];
            acc[0][0] += a0 * b0; acc[0][1] += a0 * b1; acc[0][2] += a0 * b2; acc[0][3] += a0 * b3;
            acc[1][0] += a1 * b0; acc[1][1] += a1 * b1; acc[1][2] += a1 * b2; acc[1][3] += a1 * b3;
            acc[2][0] += a2 * b0; acc[2][1] += a2 * b1; acc[2][2] += a2 * b2; acc[2][3] += a2 * b3;
            acc[3][0] += a3 * b0; acc[3][1] += a3 * b1; acc[3][2] += a3 * b2; acc[3][3] += a3 * b3;
        }
        __syncthreads();
    }

    #pragma unroll
    for (int i = 0; i < 4; ++i) {
        int row = bm + ty * 4 + i;
        if (row >= M) continue;
        #pragma unroll
        for (int j = 0; j < 4; ++j) {
            int col = bn + tx * 4 + j;
            if (col >= Nn) continue;
            float v = acc[i][j];
            if (bias) v += bias[col];
            C[(size_t)row * ldc + col] = v;
        }
    }
}

// =======================================================================
// helpers
// =======================================================================
__global__ __launch_bounds__(256) void mean_feat_kernel(const float* __restrict__ features,
                                                        float* __restrict__ mean_f)
{
    int idx = blockIdx.x * 256 + threadIdx.x;
    int b = idx >> 11, e = idx & 2047;
    float s = 0.f;
    for (int n = 0; n < NF; ++n)
        s += features[((size_t)(b * NF + n)) * EDIM + e];
    mean_f[idx] = s * (1.0f / NF);
}

__global__ __launch_bounds__(256) void gather_embed_kernel(const int* __restrict__ captions,
                                                           const float* __restrict__ embedding,
                                                           float* __restrict__ embeds)
{
    int idx = blockIdx.x * 256 + threadIdx.x;
    int m = idx >> 9;
    int j = idx & 511;
    int b = m / TT, t = m - b * TT;
    int word = captions[b * (TT + 1) + t];
    embeds[idx] = embedding[(size_t)word * EMBD + j];
}

__global__ __launch_bounds__(256) void bias_sum_kernel(const float* __restrict__ b_ih,
                                                       const float* __restrict__ b_hh,
                                                       float* __restrict__ bsum)
{
    int j = blockIdx.x * 256 + threadIdx.x;
    if (j < G4) bsum[j] = b_ih[j] + b_hh[j];
}

// concat [Ua_w; W_hh] rows (both K=512) and bias [Ua_b; 0]
__global__ __launch_bounds__(256) void build_uwcat_kernel(const float* __restrict__ Ua_w,
                                                          const float* __restrict__ Ua_b,
                                                          const float* __restrict__ W_hh,
                                                          float* __restrict__ UWcat,
                                                          float* __restrict__ biascat)
{
    int idx = blockIdx.x * 256 + threadIdx.x;
    const int NUa = DDIM * DDIM;           // 262144
    const int NTot = UWN * DDIM;           // 1310720
    if (idx < NTot)
        UWcat[idx] = (idx < NUa) ? Ua_w[idx] : W_hh[idx - NUa];
    if (idx < UWN)
        biascat[idx] = (idx < DDIM) ? Ua_b[idx] : 0.f;
}

// =======================================================================
// fused per-step: attention scores + softmax + gate assembly + LSTM cell
// one block per batch element
// =======================================================================
__global__ __launch_bounds__(256) void attend_lstm_kernel(
    const float* __restrict__ f_proj,   // B*NF*D
    const float* __restrict__ hp_g,     // B x 2560 = [h_proj | gates_mm]
    const float* __restrict__ Va_w,
    const float* __restrict__ Va_b,
    const float* __restrict__ F_ih,     // B*NF*G4
    const float* __restrict__ E_ih,     // (B*T) x G4  (includes b_ih+b_hh)
    float* __restrict__ h,
    float* __restrict__ c,
    float* __restrict__ H_all,          // (B*T) x D
    float* __restrict__ out_w,          // B*T*NF
    int t)
{
    const int b = blockIdx.x;
    const int tid = threadIdx.x;
    const int wave = tid >> 6;
    const int lane = tid & 63;
    __shared__ float s[64];
    __shared__ float gate_s[G4];

    const float* hp = hp_g + (size_t)b * UWN;
    for (int n = wave; n < NF; n += 4) {
        const float* fp = f_proj + ((size_t)(b * NF + n)) * DDIM;
        float sum = 0.f;
        for (int d = lane; d < DDIM; d += 64)
            sum += Va_w[d] * tanhf(fp[d] + hp[d]);
        for (int off = 32; off; off >>= 1) sum += __shfl_down(sum, off);
        if (lane == 0) s[n] = sum + Va_b[0];
    }
    __syncthreads();
    if (tid < 64) {
        float v = (lane < NF) ? s[lane] : -1e30f;
        float mx = v;
        for (int off = 32; off; off >>= 1) mx = fmaxf(mx, __shfl_xor(mx, off));
        float e = (lane < NF) ? expf(v - mx) : 0.f;
        float sm = e;
        for (int off = 32; off; off >>= 1) sm += __shfl_xor(sm, off);
        float p = e / sm;
        if (lane < NF) {
            s[lane] = p;
            out_w[((size_t)b * TT + t) * NF + lane] = p;
        }
    }
    __syncthreads();

    const float* gmm = hp + DDIM;
    const float* eih = E_ih + ((size_t)b * TT + t) * G4;
    const float* fib = F_ih + (size_t)b * NF * G4;
    for (int j = tid; j < G4; j += 256) {
        float acc = gmm[j] + eih[j];
        #pragma unroll 7
        for (int n = 0; n < NF; ++n)
            acc += s[n] * fib[(size_t)n * G4 + j];
        gate_s[j] = acc;
    }
    __syncthreads();

    for (int j = tid; j < DDIM; j += 256) {
        float iv = sigmoidf(gate_s[j]);
        float fv = sigmoidf(gate_s[j + DDIM]);
        float gv = tanhf(gate_s[j + 2 * DDIM]);
        float ov = sigmoidf(gate_s[j + 3 * DDIM]);
        int idx = b * DDIM + j;
        float c2 = fv * c[idx] + iv * gv;
        float h2 = ov * tanhf(c2);
        c[idx] = c2;
        h[idx] = h2;
        H_all[((size_t)b * TT + t) * DDIM + j] = h2;
    }
}

// =======================================================================
// host side
// =======================================================================
static void launch_gemm_f32(hipStream_t stream,
                            const float* A, int lda, const float* W, int ldw,
                            float* C, int ldc, const float* bias,
                            int M, int Nn, int K)
{
    dim3 grid((Nn + BN - 1) / BN, (M + BM - 1) / BM);
    dim3 block(16, 16);
    hipLaunchKernelGGL(gemm_f32, grid, block, 0, stream,
                       A, lda, W, ldw, C, ldc, bias, M, Nn, K);
}

static void launch_gemm_mfma(hipStream_t stream,
                             const float* A, int lda, const float* W, int ldw,
                             float* C, int ldc, const float* bias,
                             int M, int Nn, int K)
{
    dim3 grid((Nn + 127) / 128, M / 128);
    hipLaunchKernelGGL(gemm_bf16x3, grid, dim3(256), 0, stream,
                       A, lda, W, ldw, C, ldc, bias, Nn, K);
}

extern "C" void kernel_launch(void* const* d_in, const int* in_sizes, int n_in,
                              void* d_out, int out_size, void* d_ws, size_t ws_size,
                              hipStream_t stream)
{
    const float* features = (const float*)d_in[0];
    const int*   captions = (const int*)d_in[1];
    const float* embedding= (const float*)d_in[2];
    const float* Wa_w = (const float*)d_in[3];
    const float* Wa_b = (const float*)d_in[4];
    const float* Ua_w = (const float*)d_in[5];
    const float* Ua_b = (const float*)d_in[6];
    const float* Va_w = (const float*)d_in[7];
    const float* Va_b = (const float*)d_in[8];
    const float* W_ih = (const float*)d_in[9];
    const float* W_hh = (const float*)d_in[10];
    const float* b_ih = (const float*)d_in[11];
    const float* b_hh = (const float*)d_in[12];
    const float* ih_w = (const float*)d_in[13];
    const float* ih_b = (const float*)d_in[14];
    const float* ic_w = (const float*)d_in[15];
    const float* ic_b = (const float*)d_in[16];
    const float* fc_w = (const float*)d_in[17];
    const float* fc_b = (const float*)d_in[18];

    float* out_w = (float*)d_out;
    float* out_p = out_w + (size_t)BATCH * TT * NF;

    float* ws = (float*)d_ws;
    float* f_proj  = ws;                       // 3,211,264
    float* F_ih    = f_proj + 3211264;         // 12,845,056
    float* E_ih    = F_ih + 12845056;          // 5,505,024
    float* embeds  = E_ih + 5505024;           // 1,376,256
    float* H_all   = embeds + 1376256;         // 1,376,256
    float* mean_f  = H_all + 1376256;          // 262,144
    float* h       = mean_f + 262144;          // 65,536
    float* c       = h + 65536;                // 65,536
    float* hp_g    = c + 65536;                // 327,680
    float* UWcat   = hp_g + 327680;            // 1,310,720
    float* biascat = UWcat + 1310720;          // 2,560
    float* bsum    = biascat + 2560;           // 2,048

    // ---- init (parallel) ----
    hipLaunchKernelGGL(mean_feat_kernel, dim3(BATCH * EDIM / 256), dim3(256), 0, stream,
                       features, mean_f);
    launch_gemm_f32(stream, mean_f, EDIM, ih_w, EDIM, h, DDIM, ih_b, BATCH, DDIM, EDIM);
    launch_gemm_f32(stream, mean_f, EDIM, ic_w, EDIM, c, DDIM, ic_b, BATCH, DDIM, EDIM);
    hipLaunchKernelGGL(gather_embed_kernel, dim3(BATCH * TT * EMBD / 256), dim3(256), 0, stream,
                       captions, embedding, embeds);
    hipLaunchKernelGGL(bias_sum_kernel, dim3((G4 + 255) / 256), dim3(256), 0, stream,
                       b_ih, b_hh, bsum);
    hipLaunchKernelGGL(build_uwcat_kernel, dim3((UWN * DDIM + 255) / 256), dim3(256), 0, stream,
                       Ua_w, Ua_b, W_hh, UWcat, biascat);

    // ---- big GEMMs (bf16x3 MFMA) ----
    // f_proj = features @ Wa_w.T + Wa_b
    launch_gemm_mfma(stream, features, EDIM, Wa_w, EDIM, f_proj, DDIM, Wa_b,
                     BATCH * NF, DDIM, EDIM);
    // F_ih = features @ W_ih[:, :E].T
    launch_gemm_mfma(stream, features, EDIM, W_ih, EDIM + EMBD, F_ih, G4, nullptr,
                     BATCH * NF, G4, EDIM);
    // E_ih = embeds @ W_ih[:, E:].T + (b_ih + b_hh)
    launch_gemm_mfma(stream, embeds, EMBD, W_ih + EDIM, EDIM + EMBD, E_ih, G4, bsum,
                     BATCH * TT, G4, EMBD);

    // ---- sequential time loop (2 launches/step) ----
    for (int t = 0; t < TT; ++t) {
        // hp_g = h @ [Ua_w; W_hh].T + [Ua_b; 0]
        launch_gemm_f32(stream, h, DDIM, UWcat, DDIM, hp_g, UWN, biascat,
                        BATCH, UWN, DDIM);
        hipLaunchKernelGGL(attend_lstm_kernel, dim3(BATCH), dim3(256), 0, stream,
                           f_proj, hp_g, Va_w, Va_b, F_ih, E_ih, h, c, H_all, out_w, t);
    }

    // ---- preds = H_all @ fc_w.T + fc_b ----
    launch_gemm_mfma(stream, H_all, DDIM, fc_w, DDIM, out_p, VOC, fc_b,
                     BATCH * TT, VOC, DDIM);
}

// Round 5
// 2240.280 us; speedup vs baseline: 2.7611x; 1.5140x over previous
//
#include <hip/hip_runtime.h>
#include <math.h>

#define BATCH 128
#define NF 49
#define EDIM 2048
#define EMBD 512
#define DDIM 512
#define VOC 12000
#define TT 21
#define G4 2048   // 4*D
#define UWN 2560  // 512 + 2048

typedef __bf16 bf16x8 __attribute__((ext_vector_type(8)));
typedef float f32x4 __attribute__((ext_vector_type(4)));
typedef unsigned short ushortx8 __attribute__((ext_vector_type(8)));

union U8 { ushortx8 u; bf16x8 b; };

__device__ __forceinline__ unsigned short bf16_rne(float x) {
    union { float f; unsigned u; } v; v.f = x;
    unsigned r = v.u + 0x7fffu + ((v.u >> 16) & 1u);
    return (unsigned short)(r >> 16);
}
__device__ __forceinline__ float bf16_to_f(unsigned short h) {
    union { unsigned u; float f; } v; v.u = ((unsigned)h) << 16;
    return v.f;
}
__device__ __forceinline__ float sigmoidf(float x) { return 1.f / (1.f + expf(-x)); }

// =======================================================================
// bf16x3 split-precision MFMA GEMM (unchanged from R4 — proven)
// =======================================================================
__global__ __launch_bounds__(256) void gemm_bf16x3(
    const float* __restrict__ A, int lda,
    const float* __restrict__ W, int ldw,
    float* __restrict__ C, int ldc,
    const float* __restrict__ bias,
    int Nn, int K)
{
    __shared__ unsigned short Ah[128 * 32];
    __shared__ unsigned short Al[128 * 32];
    __shared__ unsigned short Wh[128 * 32];
    __shared__ unsigned short Wl[128 * 32];

    const int nbx = gridDim.x;
    const int nwg = nbx * gridDim.y;
    const int orig = blockIdx.y * nbx + blockIdx.x;
    const int q = nwg >> 3, r = nwg & 7;
    const int xcd = orig & 7, pos = orig >> 3;
    const int swz = (xcd < r ? xcd * (q + 1) : r * (q + 1) + (xcd - r) * q) + pos;
    const int by = swz / nbx, bx = swz - by * nbx;

    const int bm = by * 128;
    const int bn = bx * 128;
    const int tid = threadIdx.x;
    const int lane = tid & 63;
    const int wid = tid >> 6;
    const int wr = (wid >> 1) * 64;
    const int wc = (wid & 1) * 64;

    const int srow = tid >> 1;
    const int scol = (tid & 1) * 16;
    const int slotbase = scol >> 3;

    const int fr = lane & 15;
    const int ksl = lane >> 4;

    f32x4 acc[4][4] = {};

    const float* asrc0 = A + (size_t)(bm + srow) * lda + scol;
    const int wrow = bn + srow;
    const bool wok = wrow < Nn;
    const float* wsrc0 = W + (size_t)wrow * ldw + scol;

    for (int k0 = 0; k0 < K; k0 += 32) {
        {
            ushortx8 h0v, h1v, l0v, l1v;
            const float* src = asrc0 + k0;
            #pragma unroll
            for (int v = 0; v < 4; ++v) {
                float4 f = *(const float4*)(src + 4 * v);
                #define SPL(val, qq) { unsigned short hh = bf16_rne(val); \
                    unsigned short ll = bf16_rne((val) - bf16_to_f(hh)); \
                    if ((qq) < 8) { h0v[(qq)] = hh; l0v[(qq)] = ll; } \
                    else { h1v[(qq)-8] = hh; l1v[(qq)-8] = ll; } }
                SPL(f.x, 4 * v + 0) SPL(f.y, 4 * v + 1)
                SPL(f.z, 4 * v + 2) SPL(f.w, 4 * v + 3)
            }
            int sl0 = ((slotbase + 0) ^ (srow & 3)) * 8;
            int sl1 = ((slotbase + 1) ^ (srow & 3)) * 8;
            *(ushortx8*)&Ah[srow * 32 + sl0] = h0v;
            *(ushortx8*)&Ah[srow * 32 + sl1] = h1v;
            *(ushortx8*)&Al[srow * 32 + sl0] = l0v;
            *(ushortx8*)&Al[srow * 32 + sl1] = l1v;
        }
        {
            ushortx8 h0v, h1v, l0v, l1v;
            const float* src = wsrc0 + k0;
            #pragma unroll
            for (int v = 0; v < 4; ++v) {
                float4 f = wok ? *(const float4*)(src + 4 * v)
                               : make_float4(0.f, 0.f, 0.f, 0.f);
                SPL(f.x, 4 * v + 0) SPL(f.y, 4 * v + 1)
                SPL(f.z, 4 * v + 2) SPL(f.w, 4 * v + 3)
                #undef SPL
            }
            int sl0 = ((slotbase + 0) ^ (srow & 3)) * 8;
            int sl1 = ((slotbase + 1) ^ (srow & 3)) * 8;
            *(ushortx8*)&Wh[srow * 32 + sl0] = h0v;
            *(ushortx8*)&Wh[srow * 32 + sl1] = h1v;
            *(ushortx8*)&Wl[srow * 32 + sl0] = l0v;
            *(ushortx8*)&Wl[srow * 32 + sl1] = l1v;
        }
        __syncthreads();

        bf16x8 av_h[4], av_l[4], wv_h[4], wv_l[4];
        #pragma unroll
        for (int m = 0; m < 4; ++m) {
            int ar = wr + m * 16 + fr;
            int sl = (ksl ^ (ar & 3)) * 8;
            av_h[m] = *(const bf16x8*)&Ah[ar * 32 + sl];
            av_l[m] = *(const bf16x8*)&Al[ar * 32 + sl];
        }
        #pragma unroll
        for (int n = 0; n < 4; ++n) {
            int wrw = wc + n * 16 + fr;
            int sl = (ksl ^ (wrw & 3)) * 8;
            wv_h[n] = *(const bf16x8*)&Wh[wrw * 32 + sl];
            wv_l[n] = *(const bf16x8*)&Wl[wrw * 32 + sl];
        }
        #pragma unroll
        for (int m = 0; m < 4; ++m)
            #pragma unroll
            for (int n = 0; n < 4; ++n) {
                acc[m][n] = __builtin_amdgcn_mfma_f32_16x16x32_bf16(av_h[m], wv_h[n], acc[m][n], 0, 0, 0);
                acc[m][n] = __builtin_amdgcn_mfma_f32_16x16x32_bf16(av_h[m], wv_l[n], acc[m][n], 0, 0, 0);
                acc[m][n] = __builtin_amdgcn_mfma_f32_16x16x32_bf16(av_l[m], wv_h[n], acc[m][n], 0, 0, 0);
            }
        __syncthreads();
    }

    #pragma unroll
    for (int n = 0; n < 4; ++n) {
        int col = bn + wc + n * 16 + (lane & 15);
        if (col >= Nn) continue;
        float bv = bias ? bias[col] : 0.f;
        #pragma unroll
        for (int m = 0; m < 4; ++m) {
            int row0 = bm + wr + m * 16 + (lane >> 4) * 4;
            #pragma unroll
            for (int rg = 0; rg < 4; ++rg)
                C[(size_t)(row0 + rg) * ldc + col] = acc[m][n][rg] + bv;
        }
    }
}

// =======================================================================
// small MFMA GEMM for M=128: one wave per 16x16 output tile, no LDS.
// A f32 [128][lda], W pre-split bf16 hi/lo [N][K], C[128][ldc] = A*W^T + bias
// grid = N/8 blocks of 256 threads (4 waves). K multiple of 32.
// =======================================================================
__global__ __launch_bounds__(256) void small_mfma_gemm(
    const float* __restrict__ A, int lda,
    const unsigned short* __restrict__ Whi,
    const unsigned short* __restrict__ Wlo,
    int K,
    const float* __restrict__ bias,
    float* __restrict__ C, int ldc)
{
    const int tid = threadIdx.x;
    const int wave = tid >> 6;
    const int lane = tid & 63;
    const int g = blockIdx.x * 4 + wave;
    const int mt = g & 7;        // M-tile (8 x 16 = 128)
    const int nt = g >> 3;       // N-tile
    const int fr = lane & 15;
    const int ksl = lane >> 4;   // k-slot

    const float* arow = A + (size_t)(mt * 16 + fr) * lda + ksl * 8;
    const unsigned short* bhi = Whi + (size_t)(nt * 16 + fr) * K + ksl * 8;
    const unsigned short* blo = Wlo + (size_t)(nt * 16 + fr) * K + ksl * 8;

    f32x4 acc = {};
    for (int k0 = 0; k0 < K; k0 += 32) {
        float4 f0 = *(const float4*)(arow + k0);
        float4 f1 = *(const float4*)(arow + k0 + 4);
        U8 ah, al;
        float fv[8] = {f0.x, f0.y, f0.z, f0.w, f1.x, f1.y, f1.z, f1.w};
        #pragma unroll
        for (int j = 0; j < 8; ++j) {
            unsigned short hh = bf16_rne(fv[j]);
            ah.u[j] = hh;
            al.u[j] = bf16_rne(fv[j] - bf16_to_f(hh));
        }
        U8 bh, bl;
        bh.u = *(const ushortx8*)(bhi + k0);
        bl.u = *(const ushortx8*)(blo + k0);
        acc = __builtin_amdgcn_mfma_f32_16x16x32_bf16(ah.b, bh.b, acc, 0, 0, 0);
        acc = __builtin_amdgcn_mfma_f32_16x16x32_bf16(ah.b, bl.b, acc, 0, 0, 0);
        acc = __builtin_amdgcn_mfma_f32_16x16x32_bf16(al.b, bh.b, acc, 0, 0, 0);
    }

    const int n = nt * 16 + (lane & 15);
    const int m0 = mt * 16 + (lane >> 4) * 4;
    const float bv = bias ? bias[n] : 0.f;
    #pragma unroll
    for (int rg = 0; rg < 4; ++rg)
        C[(size_t)(m0 + rg) * ldc + n] = acc[rg] + bv;
}

// =======================================================================
// helpers
// =======================================================================
__global__ __launch_bounds__(256) void split_pair_kernel(const float* __restrict__ src,
                                                         unsigned short* __restrict__ hi,
                                                         unsigned short* __restrict__ lo,
                                                         int n)
{
    int idx = blockIdx.x * 256 + threadIdx.x;
    if (idx >= n) return;
    float v = src[idx];
    unsigned short h = bf16_rne(v);
    hi[idx] = h;
    lo[idx] = bf16_rne(v - bf16_to_f(h));
}

// build [Ua_w ; W_hh] split (rows n<512 from Ua_w, else W_hh) + biascat
__global__ __launch_bounds__(256) void uw_split_kernel(const float* __restrict__ Ua_w,
                                                       const float* __restrict__ Ua_b,
                                                       const float* __restrict__ W_hh,
                                                       unsigned short* __restrict__ hi,
                                                       unsigned short* __restrict__ lo,
                                                       float* __restrict__ biascat)
{
    int idx = blockIdx.x * 256 + threadIdx.x;
    if (idx < UWN * DDIM) {
        int n = idx >> 9, k = idx & 511;
        float v = (n < DDIM) ? Ua_w[n * DDIM + k] : W_hh[(size_t)(n - DDIM) * DDIM + k];
        unsigned short h = bf16_rne(v);
        hi[idx] = h;
        lo[idx] = bf16_rne(v - bf16_to_f(h));
    }
    if (idx < UWN)
        biascat[idx] = (idx < DDIM) ? Ua_b[idx] : 0.f;
}

__global__ __launch_bounds__(256) void mean_feat_kernel(const float* __restrict__ features,
                                                        float* __restrict__ mean_f)
{
    int idx = blockIdx.x * 256 + threadIdx.x;
    int b = idx >> 11, e = idx & 2047;
    float s = 0.f;
    for (int n = 0; n < NF; ++n)
        s += features[((size_t)(b * NF + n)) * EDIM + e];
    mean_f[idx] = s * (1.0f / NF);
}

__global__ __launch_bounds__(256) void gather_embed_kernel(const int* __restrict__ captions,
                                                           const float* __restrict__ embedding,
                                                           float* __restrict__ embeds)
{
    int idx = blockIdx.x * 256 + threadIdx.x;
    int m = idx >> 9;
    int j = idx & 511;
    int b = m / TT, t = m - b * TT;
    int word = captions[b * (TT + 1) + t];
    embeds[idx] = embedding[(size_t)word * EMBD + j];
}

__global__ __launch_bounds__(256) void bias_sum_kernel(const float* __restrict__ b_ih,
                                                       const float* __restrict__ b_hh,
                                                       float* __restrict__ bsum)
{
    int j = blockIdx.x * 256 + threadIdx.x;
    if (j < G4) bsum[j] = b_ih[j] + b_hh[j];
}

// =======================================================================
// per-step: scores + softmax -> sbuf[b][64], out_w
// =======================================================================
__global__ __launch_bounds__(256) void score_softmax_kernel(
    const float* __restrict__ f_proj,
    const float* __restrict__ hp_g,     // B x 2560, first 512 = h_proj
    const float* __restrict__ Va_w,
    const float* __restrict__ Va_b,
    float* __restrict__ sbuf,           // B x 64
    float* __restrict__ out_w,
    int t)
{
    const int b = blockIdx.x;
    const int tid = threadIdx.x;
    const int wave = tid >> 6;
    const int lane = tid & 63;
    __shared__ float s[64];

    const float* hp = hp_g + (size_t)b * UWN;
    for (int n = wave; n < NF; n += 4) {
        const float* fp = f_proj + ((size_t)(b * NF + n)) * DDIM;
        float sum = 0.f;
        for (int d = lane; d < DDIM; d += 64)
            sum += Va_w[d] * tanhf(fp[d] + hp[d]);
        for (int off = 32; off; off >>= 1) sum += __shfl_down(sum, off);
        if (lane == 0) s[n] = sum + Va_b[0];
    }
    __syncthreads();
    if (tid < 64) {
        float v = (lane < NF) ? s[lane] : -1e30f;
        float mx = v;
        for (int off = 32; off; off >>= 1) mx = fmaxf(mx, __shfl_xor(mx, off));
        float e = (lane < NF) ? expf(v - mx) : 0.f;
        float sm = e;
        for (int off = 32; off; off >>= 1) sm += __shfl_xor(sm, off);
        float p = e / sm;
        sbuf[b * 64 + lane] = (lane < NF) ? p : 0.f;
        if (lane < NF)
            out_w[((size_t)b * TT + t) * NF + lane] = p;
    }
}

// =======================================================================
// per-step: gate assembly (ctx @ W_ih via F_ih, + E_ih + hh) + LSTM cell
// grid 512 = (b, quarter of D), 128 threads = one D-col each
// =======================================================================
__global__ __launch_bounds__(128) void gates_lstm_kernel(
    const float* __restrict__ sbuf,     // B x 64
    const float* __restrict__ hp_g,     // B x 2560 (cols 512.. = hh-proj of gates)
    const float* __restrict__ E_ih,     // (B*T) x G4 (includes b_ih + b_hh)
    const float* __restrict__ F_ih,     // B*NF*G4
    float* __restrict__ h,
    float* __restrict__ c,
    float* __restrict__ H_all,
    int t)
{
    const int b = blockIdx.x >> 2;
    const int qd = blockIdx.x & 3;
    const int tid = threadIdx.x;
    const int j = qd * 128 + tid;       // D col

    __shared__ float sv[64];
    if (tid < 64) sv[tid] = sbuf[b * 64 + tid];
    __syncthreads();

    const float* hpg = hp_g + (size_t)b * UWN + DDIM;
    const float* eih = E_ih + ((size_t)b * TT + t) * G4;
    const float* fib = F_ih + (size_t)b * NF * G4;

    float a0 = hpg[j]            + eih[j];
    float a1 = hpg[j + DDIM]     + eih[j + DDIM];
    float a2 = hpg[j + 2 * DDIM] + eih[j + 2 * DDIM];
    float a3 = hpg[j + 3 * DDIM] + eih[j + 3 * DDIM];

    #pragma unroll 7
    for (int n = 0; n < NF; ++n) {
        float w = sv[n];
        const float* fp = fib + (size_t)n * G4;
        a0 += w * fp[j];
        a1 += w * fp[j + DDIM];
        a2 += w * fp[j + 2 * DDIM];
        a3 += w * fp[j + 3 * DDIM];
    }

    float iv = sigmoidf(a0);
    float fv = sigmoidf(a1);
    float gv = tanhf(a2);
    float ov = sigmoidf(a3);
    int idx = b * DDIM + j;
    float c2 = fv * c[idx] + iv * gv;
    float h2 = ov * tanhf(c2);
    c[idx] = c2;
    h[idx] = h2;
    H_all[((size_t)b * TT + t) * DDIM + j] = h2;
}

// =======================================================================
// host side
// =======================================================================
static void launch_gemm_mfma(hipStream_t stream,
                             const float* A, int lda, const float* W, int ldw,
                             float* C, int ldc, const float* bias,
                             int M, int Nn, int K)
{
    dim3 grid((Nn + 127) / 128, M / 128);
    hipLaunchKernelGGL(gemm_bf16x3, grid, dim3(256), 0, stream,
                       A, lda, W, ldw, C, ldc, bias, Nn, K);
}

extern "C" void kernel_launch(void* const* d_in, const int* in_sizes, int n_in,
                              void* d_out, int out_size, void* d_ws, size_t ws_size,
                              hipStream_t stream)
{
    const float* features = (const float*)d_in[0];
    const int*   captions = (const int*)d_in[1];
    const float* embedding= (const float*)d_in[2];
    const float* Wa_w = (const float*)d_in[3];
    const float* Wa_b = (const float*)d_in[4];
    const float* Ua_w = (const float*)d_in[5];
    const float* Ua_b = (const float*)d_in[6];
    const float* Va_w = (const float*)d_in[7];
    const float* Va_b = (const float*)d_in[8];
    const float* W_ih = (const float*)d_in[9];
    const float* W_hh = (const float*)d_in[10];
    const float* b_ih = (const float*)d_in[11];
    const float* b_hh = (const float*)d_in[12];
    const float* ih_w = (const float*)d_in[13];
    const float* ih_b = (const float*)d_in[14];
    const float* ic_w = (const float*)d_in[15];
    const float* ic_b = (const float*)d_in[16];
    const float* fc_w = (const float*)d_in[17];
    const float* fc_b = (const float*)d_in[18];

    float* out_w = (float*)d_out;
    float* out_p = out_w + (size_t)BATCH * TT * NF;

    float* ws = (float*)d_ws;
    float* f_proj  = ws;                       // 3,211,264
    float* F_ih    = f_proj + 3211264;         // 12,845,056
    float* E_ih    = F_ih + 12845056;          // 5,505,024
    float* embeds  = E_ih + 5505024;           // 1,376,256 (also temp for ih/ic splits)
    float* H_all   = embeds + 1376256;         // 1,376,256
    float* mean_f  = H_all + 1376256;          // 262,144
    float* h       = mean_f + 262144;          // 65,536
    float* c       = h + 65536;                // 65,536
    float* hp_g    = c + 65536;                // 327,680
    float* uwsplit = hp_g + 327680;            // 1,310,720 floats = hi+lo ushort
    float* biascat = uwsplit + 1310720;        // 2,560
    float* bsum    = biascat + 2560;           // 2,048
    float* sbuf    = bsum + 2048;              // 8,192

    unsigned short* UWhi = (unsigned short*)uwsplit;            // 1,310,720 ush
    unsigned short* UWlo = UWhi + (size_t)UWN * DDIM;           // 1,310,720 ush
    // temp split area for ih_w / ic_w (512x2048 = 1,048,576), overlaid on embeds
    unsigned short* Thi = (unsigned short*)embeds;
    unsigned short* Tlo = Thi + (size_t)DDIM * EDIM;

    // ---- init ----
    // h0 = mean_f @ ih_w.T + ih_b  (via temp split, before embeds is built)
    hipLaunchKernelGGL(split_pair_kernel, dim3((DDIM * EDIM + 255) / 256), dim3(256), 0, stream,
                       ih_w, Thi, Tlo, DDIM * EDIM);
    hipLaunchKernelGGL(mean_feat_kernel, dim3(BATCH * EDIM / 256), dim3(256), 0, stream,
                       features, mean_f);
    hipLaunchKernelGGL(small_mfma_gemm, dim3(DDIM / 8), dim3(256), 0, stream,
                       mean_f, EDIM, Thi, Tlo, EDIM, ih_b, h, DDIM);
    // c0 = mean_f @ ic_w.T + ic_b  (reuse temp split area)
    hipLaunchKernelGGL(split_pair_kernel, dim3((DDIM * EDIM + 255) / 256), dim3(256), 0, stream,
                       ic_w, Thi, Tlo, DDIM * EDIM);
    hipLaunchKernelGGL(small_mfma_gemm, dim3(DDIM / 8), dim3(256), 0, stream,
                       mean_f, EDIM, Thi, Tlo, EDIM, ic_b, c, DDIM);
    // now embeds can overwrite the temp area
    hipLaunchKernelGGL(gather_embed_kernel, dim3(BATCH * TT * EMBD / 256), dim3(256), 0, stream,
                       captions, embedding, embeds);
    hipLaunchKernelGGL(bias_sum_kernel, dim3((G4 + 255) / 256), dim3(256), 0, stream,
                       b_ih, b_hh, bsum);
    hipLaunchKernelGGL(uw_split_kernel, dim3((UWN * DDIM + 255) / 256), dim3(256), 0, stream,
                       Ua_w, Ua_b, W_hh, UWhi, UWlo, biascat);

    // ---- big GEMMs (bf16x3 MFMA) ----
    launch_gemm_mfma(stream, features, EDIM, Wa_w, EDIM, f_proj, DDIM, Wa_b,
                     BATCH * NF, DDIM, EDIM);
    launch_gemm_mfma(stream, features, EDIM, W_ih, EDIM + EMBD, F_ih, G4, nullptr,
                     BATCH * NF, G4, EDIM);
    launch_gemm_mfma(stream, embeds, EMBD, W_ih + EDIM, EDIM + EMBD, E_ih, G4, bsum,
                     BATCH * TT, G4, EMBD);

    // ---- sequential time loop (3 small launches/step) ----
    for (int t = 0; t < TT; ++t) {
        // hp_g = h @ [Ua_w; W_hh].T + [Ua_b; 0]   (128 x 2560, K=512)
        hipLaunchKernelGGL(small_mfma_gemm, dim3(UWN / 8), dim3(256), 0, stream,
                           h, DDIM, UWhi, UWlo, DDIM, biascat, hp_g, UWN);
        hipLaunchKernelGGL(score_softmax_kernel, dim3(BATCH), dim3(256), 0, stream,
                           f_proj, hp_g, Va_w, Va_b, sbuf, out_w, t);
        hipLaunchKernelGGL(gates_lstm_kernel, dim3(BATCH * 4), dim3(128), 0, stream,
                           sbuf, hp_g, E_ih, F_ih, h, c, H_all, t);
    }

    // ---- preds = H_all @ fc_w.T + fc_b ----
    launch_gemm_mfma(stream, H_all, DDIM, fc_w, DDIM, out_p, VOC, fc_b,
                     BATCH * TT, VOC, DDIM);
}

// Round 6
// 2018.091 us; speedup vs baseline: 3.0651x; 1.1101x over previous
//
#include <hip/hip_runtime.h>
#include <math.h>
#include <stdint.h>

#define BATCH 128
#define NF 49
#define EDIM 2048
#define EMBD 512
#define DDIM 512
#define VOC 12000
#define VOCP 12032
#define TT 21
#define G4 2048   // 4*D
#define UWN 2560  // 512 + 2048

typedef __bf16 bf16x8 __attribute__((ext_vector_type(8)));
typedef float f32x4 __attribute__((ext_vector_type(4)));
typedef unsigned short ushortx8 __attribute__((ext_vector_type(8)));
typedef unsigned short u16;

union U8 { ushortx8 u; bf16x8 b; };

__device__ __forceinline__ u16 bf16_rne(float x) {
    union { float f; unsigned u; } v; v.f = x;
    unsigned r = v.u + 0x7fffu + ((v.u >> 16) & 1u);
    return (u16)(r >> 16);
}
__device__ __forceinline__ float bf16_to_f(u16 h) {
    union { unsigned u; float f; } v; v.u = ((unsigned)h) << 16;
    return v.f;
}
__device__ __forceinline__ float sigmoidf(float x) { return 1.f / (1.f + expf(-x)); }

// direct global->LDS 16B async copy (CK idiom for addrspace casts)
__device__ __forceinline__ void gload16(const void* g, void* l) {
    auto gp = reinterpret_cast<const __attribute__((address_space(1))) unsigned int*>(
        reinterpret_cast<uintptr_t>(g));
    auto lp = reinterpret_cast<__attribute__((address_space(3))) unsigned int*>(
        reinterpret_cast<uintptr_t>(l));
    __builtin_amdgcn_global_load_lds(gp, lp, 16, 0, 0);
}

// =======================================================================
// NEW: pre-split bf16x3 GEMM, m97 structure (global_load_lds + swizzled LDS)
// C[m][n] = sum_k A[m][k]*W[n][k] (+bias[n]), A/W given as bf16 hi/lo pairs.
// M multiple of 128. W buffers padded to multiple of 128 rows (zeros).
// K multiple of 32. 128x128 tile, 4 waves, BK=32.
// LDS [row][slot] holds global slot^(row&3)  (slot = 16B = 8 bf16)
// =======================================================================
__global__ __launch_bounds__(256) void gemm_bf16s(
    const u16* __restrict__ Ahi, const u16* __restrict__ Alo, int lda,
    const u16* __restrict__ Whi, const u16* __restrict__ Wlo, int ldw,
    float* __restrict__ C, int ldc,
    const float* __restrict__ bias,
    int Nn, int K)
{
    __shared__ u16 Ah[128 * 32];
    __shared__ u16 Al[128 * 32];
    __shared__ u16 Wh[128 * 32];
    __shared__ u16 Wl[128 * 32];

    // bijective XCD-aware swizzle
    const int nbx = gridDim.x;
    const int nwg = nbx * gridDim.y;
    const int orig = blockIdx.y * nbx + blockIdx.x;
    const int q = nwg >> 3, r = nwg & 7;
    const int xcd = orig & 7, pos = orig >> 3;
    const int swz = (xcd < r ? xcd * (q + 1) : r * (q + 1) + (xcd - r) * q) + pos;
    const int by = swz / nbx, bx = swz - by * nbx;

    const int bm = by * 128;
    const int bn = bx * 128;
    const int tid = threadIdx.x;
    const int lane = tid & 63;
    const int wid = tid >> 6;
    const int wr = (wid >> 1) * 64;
    const int wc = (wid & 1) * 64;

    // staging: wave w stages rows [32w,32w+32) of each tile, 2 chunks of 16 rows
    const int srow = wid * 32 + (lane >> 2);            // + 16*c
    const int sslot = (lane & 3) ^ ((lane >> 2) & 3);   // pre-swizzled source slot
    const u16* a_src = Ahi + (size_t)(bm + srow) * lda + sslot * 8;
    const u16* al_src = Alo + (size_t)(bm + srow) * lda + sslot * 8;
    const u16* w_src = Whi + (size_t)(bn + srow) * ldw + sslot * 8;
    const u16* wl_src = Wlo + (size_t)(bn + srow) * ldw + sslot * 8;
    const int lds_base = (wid * 32) * 32;               // element offset, + 16*32 per chunk

    const int fr = lane & 15;
    const int ksl = lane >> 4;
    const int rsl = (ksl ^ (fr & 3)) * 8;               // swizzled read slot (elements)

    f32x4 acc[4][4] = {};

    for (int k0 = 0; k0 < K; k0 += 32) {
        #pragma unroll
        for (int cch = 0; cch < 2; ++cch) {
            const size_t go = (size_t)cch * 16 * lda + k0;
            const size_t gw = (size_t)cch * 16 * ldw + k0;
            const int lo = lds_base + cch * 16 * 32;
            gload16(a_src + go, &Ah[lo]);
            gload16(al_src + go, &Al[lo]);
            gload16(w_src + gw, &Wh[lo]);
            gload16(wl_src + gw, &Wl[lo]);
        }
        __syncthreads();

        bf16x8 av_h[4], av_l[4], wv_h[4], wv_l[4];
        #pragma unroll
        for (int m = 0; m < 4; ++m) {
            int ar = wr + m * 16 + fr;
            av_h[m] = *(const bf16x8*)&Ah[ar * 32 + rsl];
            av_l[m] = *(const bf16x8*)&Al[ar * 32 + rsl];
        }
        #pragma unroll
        for (int n = 0; n < 4; ++n) {
            int wrw = wc + n * 16 + fr;
            wv_h[n] = *(const bf16x8*)&Wh[wrw * 32 + rsl];
            wv_l[n] = *(const bf16x8*)&Wl[wrw * 32 + rsl];
        }
        #pragma unroll
        for (int m = 0; m < 4; ++m)
            #pragma unroll
            for (int n = 0; n < 4; ++n) {
                acc[m][n] = __builtin_amdgcn_mfma_f32_16x16x32_bf16(av_h[m], wv_h[n], acc[m][n], 0, 0, 0);
                acc[m][n] = __builtin_amdgcn_mfma_f32_16x16x32_bf16(av_h[m], wv_l[n], acc[m][n], 0, 0, 0);
                acc[m][n] = __builtin_amdgcn_mfma_f32_16x16x32_bf16(av_l[m], wv_h[n], acc[m][n], 0, 0, 0);
            }
        __syncthreads();
    }

    #pragma unroll
    for (int n = 0; n < 4; ++n) {
        int col = bn + wc + n * 16 + (lane & 15);
        if (col >= Nn) continue;
        float bv = bias ? bias[col] : 0.f;
        #pragma unroll
        for (int m = 0; m < 4; ++m) {
            int row0 = bm + wr + m * 16 + (lane >> 4) * 4;
            #pragma unroll
            for (int rg = 0; rg < 4; ++rg)
                C[(size_t)(row0 + rg) * ldc + col] = acc[m][n][rg] + bv;
        }
    }
}

// =======================================================================
// FALLBACK: R5's f32-input bf16x3 GEMM (in-kernel split) — proven
// =======================================================================
__global__ __launch_bounds__(256) void gemm_bf16x3(
    const float* __restrict__ A, int lda,
    const float* __restrict__ W, int ldw,
    float* __restrict__ C, int ldc,
    const float* __restrict__ bias,
    int Nn, int K)
{
    __shared__ u16 Ah[128 * 32];
    __shared__ u16 Al[128 * 32];
    __shared__ u16 Wh[128 * 32];
    __shared__ u16 Wl[128 * 32];

    const int nbx = gridDim.x;
    const int nwg = nbx * gridDim.y;
    const int orig = blockIdx.y * nbx + blockIdx.x;
    const int q = nwg >> 3, r = nwg & 7;
    const int xcd = orig & 7, pos = orig >> 3;
    const int swz = (xcd < r ? xcd * (q + 1) : r * (q + 1) + (xcd - r) * q) + pos;
    const int by = swz / nbx, bx = swz - by * nbx;

    const int bm = by * 128;
    const int bn = bx * 128;
    const int tid = threadIdx.x;
    const int lane = tid & 63;
    const int wid = tid >> 6;
    const int wr = (wid >> 1) * 64;
    const int wc = (wid & 1) * 64;

    const int srow = tid >> 1;
    const int scol = (tid & 1) * 16;
    const int slotbase = scol >> 3;

    const int fr = lane & 15;
    const int ksl = lane >> 4;

    f32x4 acc[4][4] = {};

    const float* asrc0 = A + (size_t)(bm + srow) * lda + scol;
    const int wrow = bn + srow;
    const bool wok = wrow < Nn;
    const float* wsrc0 = W + (size_t)wrow * ldw + scol;

    for (int k0 = 0; k0 < K; k0 += 32) {
        {
            ushortx8 h0v, h1v, l0v, l1v;
            const float* src = asrc0 + k0;
            #pragma unroll
            for (int v = 0; v < 4; ++v) {
                float4 f = *(const float4*)(src + 4 * v);
                #define SPL(val, qq) { u16 hh = bf16_rne(val); \
                    u16 ll = bf16_rne((val) - bf16_to_f(hh)); \
                    if ((qq) < 8) { h0v[(qq)] = hh; l0v[(qq)] = ll; } \
                    else { h1v[(qq)-8] = hh; l1v[(qq)-8] = ll; } }
                SPL(f.x, 4 * v + 0) SPL(f.y, 4 * v + 1)
                SPL(f.z, 4 * v + 2) SPL(f.w, 4 * v + 3)
            }
            int sl0 = ((slotbase + 0) ^ (srow & 3)) * 8;
            int sl1 = ((slotbase + 1) ^ (srow & 3)) * 8;
            *(ushortx8*)&Ah[srow * 32 + sl0] = h0v;
            *(ushortx8*)&Ah[srow * 32 + sl1] = h1v;
            *(ushortx8*)&Al[srow * 32 + sl0] = l0v;
            *(ushortx8*)&Al[srow * 32 + sl1] = l1v;
        }
        {
            ushortx8 h0v, h1v, l0v, l1v;
            const float* src = wsrc0 + k0;
            #pragma unroll
            for (int v = 0; v < 4; ++v) {
                float4 f = wok ? *(const float4*)(src + 4 * v)
                               : make_float4(0.f, 0.f, 0.f, 0.f);
                SPL(f.x, 4 * v + 0) SPL(f.y, 4 * v + 1)
                SPL(f.z, 4 * v + 2) SPL(f.w, 4 * v + 3)
                #undef SPL
            }
            int sl0 = ((slotbase + 0) ^ (srow & 3)) * 8;
            int sl1 = ((slotbase + 1) ^ (srow & 3)) * 8;
            *(ushortx8*)&Wh[srow * 32 + sl0] = h0v;
            *(ushortx8*)&Wh[srow * 32 + sl1] = h1v;
            *(ushortx8*)&Wl[srow * 32 + sl0] = l0v;
            *(ushortx8*)&Wl[srow * 32 + sl1] = l1v;
        }
        __syncthreads();

        bf16x8 av_h[4], av_l[4], wv_h[4], wv_l[4];
        #pragma unroll
        for (int m = 0; m < 4; ++m) {
            int ar = wr + m * 16 + fr;
            int sl = (ksl ^ (ar & 3)) * 8;
            av_h[m] = *(const bf16x8*)&Ah[ar * 32 + sl];
            av_l[m] = *(const bf16x8*)&Al[ar * 32 + sl];
        }
        #pragma unroll
        for (int n = 0; n < 4; ++n) {
            int wrw = wc + n * 16 + fr;
            int sl = (ksl ^ (wrw & 3)) * 8;
            wv_h[n] = *(const bf16x8*)&Wh[wrw * 32 + sl];
            wv_l[n] = *(const bf16x8*)&Wl[wrw * 32 + sl];
        }
        #pragma unroll
        for (int m = 0; m < 4; ++m)
            #pragma unroll
            for (int n = 0; n < 4; ++n) {
                acc[m][n] = __builtin_amdgcn_mfma_f32_16x16x32_bf16(av_h[m], wv_h[n], acc[m][n], 0, 0, 0);
                acc[m][n] = __builtin_amdgcn_mfma_f32_16x16x32_bf16(av_h[m], wv_l[n], acc[m][n], 0, 0, 0);
                acc[m][n] = __builtin_amdgcn_mfma_f32_16x16x32_bf16(av_l[m], wv_h[n], acc[m][n], 0, 0, 0);
            }
        __syncthreads();
    }

    #pragma unroll
    for (int n = 0; n < 4; ++n) {
        int col = bn + wc + n * 16 + (lane & 15);
        if (col >= Nn) continue;
        float bv = bias ? bias[col] : 0.f;
        #pragma unroll
        for (int m = 0; m < 4; ++m) {
            int row0 = bm + wr + m * 16 + (lane >> 4) * 4;
            #pragma unroll
            for (int rg = 0; rg < 4; ++rg)
                C[(size_t)(row0 + rg) * ldc + col] = acc[m][n][rg] + bv;
        }
    }
}

// =======================================================================
// small MFMA GEMM (M=128): one wave per 16x16 tile, W pre-split (shared)
// =======================================================================
__global__ __launch_bounds__(256) void small_mfma_gemm(
    const float* __restrict__ A, int lda,
    const u16* __restrict__ Whi,
    const u16* __restrict__ Wlo,
    int K,
    const float* __restrict__ bias,
    float* __restrict__ C, int ldc)
{
    const int tid = threadIdx.x;
    const int wave = tid >> 6;
    const int lane = tid & 63;
    const int g = blockIdx.x * 4 + wave;
    const int mt = g & 7;
    const int nt = g >> 3;
    const int fr = lane & 15;
    const int ksl = lane >> 4;

    const float* arow = A + (size_t)(mt * 16 + fr) * lda + ksl * 8;
    const u16* bhi = Whi + (size_t)(nt * 16 + fr) * K + ksl * 8;
    const u16* blo = Wlo + (size_t)(nt * 16 + fr) * K + ksl * 8;

    f32x4 acc = {};
    for (int k0 = 0; k0 < K; k0 += 32) {
        float4 f0 = *(const float4*)(arow + k0);
        float4 f1 = *(const float4*)(arow + k0 + 4);
        U8 ah, al;
        float fv[8] = {f0.x, f0.y, f0.z, f0.w, f1.x, f1.y, f1.z, f1.w};
        #pragma unroll
        for (int j = 0; j < 8; ++j) {
            u16 hh = bf16_rne(fv[j]);
            ah.u[j] = hh;
            al.u[j] = bf16_rne(fv[j] - bf16_to_f(hh));
        }
        U8 bh, bl;
        bh.u = *(const ushortx8*)(bhi + k0);
        bl.u = *(const ushortx8*)(blo + k0);
        acc = __builtin_amdgcn_mfma_f32_16x16x32_bf16(ah.b, bh.b, acc, 0, 0, 0);
        acc = __builtin_amdgcn_mfma_f32_16x16x32_bf16(ah.b, bl.b, acc, 0, 0, 0);
        acc = __builtin_amdgcn_mfma_f32_16x16x32_bf16(al.b, bh.b, acc, 0, 0, 0);
    }

    const int n = nt * 16 + (lane & 15);
    const int m0 = mt * 16 + (lane >> 4) * 4;
    const float bv = bias ? bias[n] : 0.f;
    #pragma unroll
    for (int rg = 0; rg < 4; ++rg)
        C[(size_t)(m0 + rg) * ldc + n] = acc[rg] + bv;
}

// =======================================================================
// helpers
// =======================================================================
// generic strided hi/lo split with optional zero-padded rows
__global__ __launch_bounds__(256) void split_mat_kernel(
    const float* __restrict__ src, int srcld, int cols, int rows, int rows_pad,
    u16* __restrict__ hi, u16* __restrict__ lo)
{
    int idx = blockIdx.x * 256 + threadIdx.x;
    if (idx >= rows_pad * cols) return;
    int r = idx / cols, k = idx - r * cols;
    float v = (r < rows) ? src[(size_t)r * srcld + k] : 0.f;
    u16 h = bf16_rne(v);
    hi[idx] = h;
    lo[idx] = bf16_rne(v - bf16_to_f(h));
}

__global__ __launch_bounds__(256) void uw_split_kernel(const float* __restrict__ Ua_w,
                                                       const float* __restrict__ Ua_b,
                                                       const float* __restrict__ W_hh,
                                                       u16* __restrict__ hi,
                                                       u16* __restrict__ lo,
                                                       float* __restrict__ biascat)
{
    int idx = blockIdx.x * 256 + threadIdx.x;
    if (idx < UWN * DDIM) {
        int n = idx >> 9, k = idx & 511;
        float v = (n < DDIM) ? Ua_w[n * DDIM + k] : W_hh[(size_t)(n - DDIM) * DDIM + k];
        u16 h = bf16_rne(v);
        hi[idx] = h;
        lo[idx] = bf16_rne(v - bf16_to_f(h));
    }
    if (idx < UWN)
        biascat[idx] = (idx < DDIM) ? Ua_b[idx] : 0.f;
}

__global__ __launch_bounds__(256) void mean_feat_kernel(const float* __restrict__ features,
                                                        float* __restrict__ mean_f)
{
    int idx = blockIdx.x * 256 + threadIdx.x;
    int b = idx >> 11, e = idx & 2047;
    float s = 0.f;
    for (int n = 0; n < NF; ++n)
        s += features[((size_t)(b * NF + n)) * EDIM + e];
    mean_f[idx] = s * (1.0f / NF);
}

// fallback: f32 embeds
__global__ __launch_bounds__(256) void gather_embed_kernel(const int* __restrict__ captions,
                                                           const float* __restrict__ embedding,
                                                           float* __restrict__ embeds)
{
    int idx = blockIdx.x * 256 + threadIdx.x;
    int m = idx >> 9;
    int j = idx & 511;
    int b = m / TT, t = m - b * TT;
    int word = captions[b * (TT + 1) + t];
    embeds[idx] = embedding[(size_t)word * EMBD + j];
}

// new: split embeds at gather time
__global__ __launch_bounds__(256) void gather_embed_split_kernel(const int* __restrict__ captions,
                                                                 const float* __restrict__ embedding,
                                                                 u16* __restrict__ ehi,
                                                                 u16* __restrict__ elo)
{
    int idx = blockIdx.x * 256 + threadIdx.x;
    int m = idx >> 9;
    int j = idx & 511;
    int b = m / TT, t = m - b * TT;
    int word = captions[b * (TT + 1) + t];
    float v = embedding[(size_t)word * EMBD + j];
    u16 h = bf16_rne(v);
    ehi[idx] = h;
    elo[idx] = bf16_rne(v - bf16_to_f(h));
}

__global__ __launch_bounds__(256) void bias_sum_kernel(const float* __restrict__ b_ih,
                                                       const float* __restrict__ b_hh,
                                                       float* __restrict__ bsum)
{
    int j = blockIdx.x * 256 + threadIdx.x;
    if (j < G4) bsum[j] = b_ih[j] + b_hh[j];
}

// =======================================================================
// NEW: fused per-step score+softmax+gates+LSTM. grid 256 = (b, half-D)
// =======================================================================
__global__ __launch_bounds__(256) void fused_step_kernel(
    const float* __restrict__ f_proj,
    const float* __restrict__ hp_g,     // B x 2560: [h_proj | hh-gates]
    const float* __restrict__ Va_w,
    const float* __restrict__ Va_b,
    const float* __restrict__ F_ih,     // B*NF*G4
    const float* __restrict__ E_ih,     // (B*T) x G4 (incl b_ih+b_hh)
    float* __restrict__ h,
    float* __restrict__ c,
    u16* __restrict__ H_hi,             // (B*T) x D bf16 hi/lo (for fc GEMM)
    u16* __restrict__ H_lo,
    float* __restrict__ out_w,
    int t)
{
    const int b = blockIdx.x >> 1;
    const int hf = blockIdx.x & 1;
    const int tid = threadIdx.x;
    const int wave = tid >> 6;
    const int lane = tid & 63;
    __shared__ float s[64];

    // scores (each of the 2 blocks per b computes redundantly)
    const float* hp = hp_g + (size_t)b * UWN;
    for (int n = wave; n < NF; n += 4) {
        const float* fp = f_proj + ((size_t)(b * NF + n)) * DDIM;
        float sum = 0.f;
        for (int d = lane; d < DDIM; d += 64)
            sum += Va_w[d] * tanhf(fp[d] + hp[d]);
        for (int off = 32; off; off >>= 1) sum += __shfl_down(sum, off);
        if (lane == 0) s[n] = sum + Va_b[0];
    }
    __syncthreads();
    if (tid < 64) {
        float v = (lane < NF) ? s[lane] : -1e30f;
        float mx = v;
        for (int off = 32; off; off >>= 1) mx = fmaxf(mx, __shfl_xor(mx, off));
        float e = (lane < NF) ? expf(v - mx) : 0.f;
        float sm = e;
        for (int off = 32; off; off >>= 1) sm += __shfl_xor(sm, off);
        float p = e / sm;
        s[lane] = (lane < NF) ? p : 0.f;
        if (hf == 0 && lane < NF)
            out_w[((size_t)b * TT + t) * NF + lane] = p;
    }
    __syncthreads();

    // gates + LSTM: thread owns D-col j
    const int j = hf * 256 + tid;
    const float* gmm = hp + DDIM;
    const float* eih = E_ih + ((size_t)b * TT + t) * G4;
    const float* fib = F_ih + (size_t)b * NF * G4;

    float a0 = gmm[j]            + eih[j];
    float a1 = gmm[j + DDIM]     + eih[j + DDIM];
    float a2 = gmm[j + 2 * DDIM] + eih[j + 2 * DDIM];
    float a3 = gmm[j + 3 * DDIM] + eih[j + 3 * DDIM];

    #pragma unroll 7
    for (int n = 0; n < NF; ++n) {
        float w = s[n];
        const float* fp = fib + (size_t)n * G4;
        a0 += w * fp[j];
        a1 += w * fp[j + DDIM];
        a2 += w * fp[j + 2 * DDIM];
        a3 += w * fp[j + 3 * DDIM];
    }

    float iv = sigmoidf(a0);
    float fv = sigmoidf(a1);
    float gv = tanhf(a2);
    float ov = sigmoidf(a3);
    int idx = b * DDIM + j;
    float c2 = fv * c[idx] + iv * gv;
    float h2 = ov * tanhf(c2);
    c[idx] = c2;
    h[idx] = h2;
    size_t hix = ((size_t)b * TT + t) * DDIM + j;
    u16 hh = bf16_rne(h2);
    H_hi[hix] = hh;
    H_lo[hix] = bf16_rne(h2 - bf16_to_f(hh));
}

// =======================================================================
// FALLBACK per-step kernels (R5, proven)
// =======================================================================
__global__ __launch_bounds__(256) void score_softmax_kernel(
    const float* __restrict__ f_proj,
    const float* __restrict__ hp_g,
    const float* __restrict__ Va_w,
    const float* __restrict__ Va_b,
    float* __restrict__ sbuf,
    float* __restrict__ out_w,
    int t)
{
    const int b = blockIdx.x;
    const int tid = threadIdx.x;
    const int wave = tid >> 6;
    const int lane = tid & 63;
    __shared__ float s[64];

    const float* hp = hp_g + (size_t)b * UWN;
    for (int n = wave; n < NF; n += 4) {
        const float* fp = f_proj + ((size_t)(b * NF + n)) * DDIM;
        float sum = 0.f;
        for (int d = lane; d < DDIM; d += 64)
            sum += Va_w[d] * tanhf(fp[d] + hp[d]);
        for (int off = 32; off; off >>= 1) sum += __shfl_down(sum, off);
        if (lane == 0) s[n] = sum + Va_b[0];
    }
    __syncthreads();
    if (tid < 64) {
        float v = (lane < NF) ? s[lane] : -1e30f;
        float mx = v;
        for (int off = 32; off; off >>= 1) mx = fmaxf(mx, __shfl_xor(mx, off));
        float e = (lane < NF) ? expf(v - mx) : 0.f;
        float sm = e;
        for (int off = 32; off; off >>= 1) sm += __shfl_xor(sm, off);
        float p = e / sm;
        sbuf[b * 64 + lane] = (lane < NF) ? p : 0.f;
        if (lane < NF)
            out_w[((size_t)b * TT + t) * NF + lane] = p;
    }
}

__global__ __launch_bounds__(128) void gates_lstm_kernel(
    const float* __restrict__ sbuf,
    const float* __restrict__ hp_g,
    const float* __restrict__ E_ih,
    const float* __restrict__ F_ih,
    float* __restrict__ h,
    float* __restrict__ c,
    float* __restrict__ H_all,
    int t)
{
    const int b = blockIdx.x >> 2;
    const int qd = blockIdx.x & 3;
    const int tid = threadIdx.x;
    const int j = qd * 128 + tid;

    __shared__ float sv[64];
    if (tid < 64) sv[tid] = sbuf[b * 64 + tid];
    __syncthreads();

    const float* hpg = hp_g + (size_t)b * UWN + DDIM;
    const float* eih = E_ih + ((size_t)b * TT + t) * G4;
    const float* fib = F_ih + (size_t)b * NF * G4;

    float a0 = hpg[j]            + eih[j];
    float a1 = hpg[j + DDIM]     + eih[j + DDIM];
    float a2 = hpg[j + 2 * DDIM] + eih[j + 2 * DDIM];
    float a3 = hpg[j + 3 * DDIM] + eih[j + 3 * DDIM];

    #pragma unroll 7
    for (int n = 0; n < NF; ++n) {
        float w = sv[n];
        const float* fp = fib + (size_t)n * G4;
        a0 += w * fp[j];
        a1 += w * fp[j + DDIM];
        a2 += w * fp[j + 2 * DDIM];
        a3 += w * fp[j + 3 * DDIM];
    }

    float iv = sigmoidf(a0);
    float fv = sigmoidf(a1);
    float gv = tanhf(a2);
    float ov = sigmoidf(a3);
    int idx = b * DDIM + j;
    float c2 = fv * c[idx] + iv * gv;
    float h2 = ov * tanhf(c2);
    c[idx] = c2;
    h[idx] = h2;
    H_all[((size_t)b * TT + t) * DDIM + j] = h2;
}

// =======================================================================
// host side
// =======================================================================
static void launch_gemm_mfma(hipStream_t stream,
                             const float* A, int lda, const float* W, int ldw,
                             float* C, int ldc, const float* bias,
                             int M, int Nn, int K)
{
    dim3 grid((Nn + 127) / 128, M / 128);
    hipLaunchKernelGGL(gemm_bf16x3, grid, dim3(256), 0, stream,
                       A, lda, W, ldw, C, ldc, bias, Nn, K);
}

static void launch_gemm_s(hipStream_t stream,
                          const u16* Ahi, const u16* Alo, int lda,
                          const u16* Whi, const u16* Wlo, int ldw,
                          float* C, int ldc, const float* bias,
                          int M, int Nn, int K)
{
    dim3 grid((Nn + 127) / 128, M / 128);
    hipLaunchKernelGGL(gemm_bf16s, grid, dim3(256), 0, stream,
                       Ahi, Alo, lda, Whi, Wlo, ldw, C, ldc, bias, Nn, K);
}

static void launch_split(hipStream_t stream, const float* src, int srcld, int cols,
                         int rows, int rows_pad, u16* hi, u16* lo)
{
    int total = rows_pad * cols;
    hipLaunchKernelGGL(split_mat_kernel, dim3((total + 255) / 256), dim3(256), 0, stream,
                       src, srcld, cols, rows, rows_pad, hi, lo);
}

extern "C" void kernel_launch(void* const* d_in, const int* in_sizes, int n_in,
                              void* d_out, int out_size, void* d_ws, size_t ws_size,
                              hipStream_t stream)
{
    const float* features = (const float*)d_in[0];
    const int*   captions = (const int*)d_in[1];
    const float* embedding= (const float*)d_in[2];
    const float* Wa_w = (const float*)d_in[3];
    const float* Wa_b = (const float*)d_in[4];
    const float* Ua_w = (const float*)d_in[5];
    const float* Ua_b = (const float*)d_in[6];
    const float* Va_w = (const float*)d_in[7];
    const float* Va_b = (const float*)d_in[8];
    const float* W_ih = (const float*)d_in[9];
    const float* W_hh = (const float*)d_in[10];
    const float* b_ih = (const float*)d_in[11];
    const float* b_hh = (const float*)d_in[12];
    const float* ih_w = (const float*)d_in[13];
    const float* ih_b = (const float*)d_in[14];
    const float* ic_w = (const float*)d_in[15];
    const float* ic_b = (const float*)d_in[16];
    const float* fc_w = (const float*)d_in[17];
    const float* fc_b = (const float*)d_in[18];

    float* out_w = (float*)d_out;
    float* out_p = out_w + (size_t)BATCH * TT * NF;

    const size_t NEED_FLOATS = 51650560ULL;   // new-path workspace (~207 MB)

    if (ws_size >= NEED_FLOATS * 4) {
        // ================= NEW PATH =================
        float* ws = (float*)d_ws;
        size_t off = 0;
        auto alloc = [&](size_t n) { float* p = ws + off; off += n; return p; };

        float* f_proj  = alloc(3211264);
        float* F_ih    = alloc(12845056);
        float* E_ih    = alloc(5505024);
        float* hp_g    = alloc(327680);
        float* mean_f  = alloc(262144);
        float* h       = alloc(65536);
        float* c       = alloc(65536);
        float* bsum    = alloc(4096);
        float* biascat = alloc(4096);
        u16* feat_hi = (u16*)alloc(6422528);
        u16* feat_lo = (u16*)alloc(6422528);
        u16* emb_hi  = (u16*)alloc(688128);
        u16* emb_lo  = (u16*)alloc(688128);
        u16* H_hi    = (u16*)alloc(688128);
        u16* H_lo    = (u16*)alloc(688128);
        u16* Wa_hi   = (u16*)alloc(524288);
        u16* Wa_lo   = (u16*)alloc(524288);
        u16* Wf_hi   = (u16*)alloc(2097152);
        u16* Wf_lo   = (u16*)alloc(2097152);
        u16* We_hi   = (u16*)alloc(524288);
        u16* We_lo   = (u16*)alloc(524288);
        u16* UW_hi   = (u16*)alloc(655360);
        u16* UW_lo   = (u16*)alloc(655360);
        u16* fcw_hi  = (u16*)alloc(3080192);
        u16* fcw_lo  = (u16*)alloc(3080192);
        // temp ih/ic split overlays the fc split area (stream-ordered before fc split)
        u16* T_hi = fcw_hi;
        u16* T_lo = fcw_lo;

        // ---- init: h0/c0 (uses T overlay), then weight/activation splits ----
        hipLaunchKernelGGL(mean_feat_kernel, dim3(BATCH * EDIM / 256), dim3(256), 0, stream,
                           features, mean_f);
        launch_split(stream, ih_w, EDIM, EDIM, DDIM, DDIM, T_hi, T_lo);
        hipLaunchKernelGGL(small_mfma_gemm, dim3(DDIM / 8), dim3(256), 0, stream,
                           mean_f, EDIM, T_hi, T_lo, EDIM, ih_b, h, DDIM);
        launch_split(stream, ic_w, EDIM, EDIM, DDIM, DDIM, T_hi, T_lo);
        hipLaunchKernelGGL(small_mfma_gemm, dim3(DDIM / 8), dim3(256), 0, stream,
                           mean_f, EDIM, T_hi, T_lo, EDIM, ic_b, c, DDIM);
        // now safe to fill fc split area
        launch_split(stream, fc_w, DDIM, DDIM, VOC, VOCP, fcw_hi, fcw_lo);

        launch_split(stream, features, EDIM, EDIM, BATCH * NF, BATCH * NF, feat_hi, feat_lo);
        launch_split(stream, Wa_w, EDIM, EDIM, DDIM, DDIM, Wa_hi, Wa_lo);
        launch_split(stream, W_ih, EDIM + EMBD, EDIM, G4, G4, Wf_hi, Wf_lo);
        launch_split(stream, W_ih + EDIM, EDIM + EMBD, EMBD, G4, G4, We_hi, We_lo);
        hipLaunchKernelGGL(gather_embed_split_kernel, dim3(BATCH * TT * EMBD / 256), dim3(256), 0, stream,
                           captions, embedding, emb_hi, emb_lo);
        hipLaunchKernelGGL(bias_sum_kernel, dim3((G4 + 255) / 256), dim3(256), 0, stream,
                           b_ih, b_hh, bsum);
        hipLaunchKernelGGL(uw_split_kernel, dim3((UWN * DDIM + 255) / 256), dim3(256), 0, stream,
                           Ua_w, Ua_b, W_hh, UW_hi, UW_lo, biascat);

        // ---- big GEMMs (pre-split bf16x3, gload_lds) ----
        launch_gemm_s(stream, feat_hi, feat_lo, EDIM, Wa_hi, Wa_lo, EDIM,
                      f_proj, DDIM, Wa_b, BATCH * NF, DDIM, EDIM);
        launch_gemm_s(stream, feat_hi, feat_lo, EDIM, Wf_hi, Wf_lo, EDIM,
                      F_ih, G4, nullptr, BATCH * NF, G4, EDIM);
        launch_gemm_s(stream, emb_hi, emb_lo, EMBD, We_hi, We_lo, EMBD,
                      E_ih, G4, bsum, BATCH * TT, G4, EMBD);

        // ---- sequential loop: 2 launches/step ----
        for (int t = 0; t < TT; ++t) {
            hipLaunchKernelGGL(small_mfma_gemm, dim3(UWN / 8), dim3(256), 0, stream,
                               h, DDIM, UW_hi, UW_lo, DDIM, biascat, hp_g, UWN);
            hipLaunchKernelGGL(fused_step_kernel, dim3(BATCH * 2), dim3(256), 0, stream,
                               f_proj, hp_g, Va_w, Va_b, F_ih, E_ih, h, c,
                               H_hi, H_lo, out_w, t);
        }

        // ---- preds ----
        launch_gemm_s(stream, H_hi, H_lo, DDIM, fcw_hi, fcw_lo, DDIM,
                      out_p, VOC, fc_b, BATCH * TT, VOC, DDIM);
    } else {
        // ================= FALLBACK: R5 path (proven) =================
        float* ws = (float*)d_ws;
        float* f_proj  = ws;
        float* F_ih    = f_proj + 3211264;
        float* E_ih    = F_ih + 12845056;
        float* embeds  = E_ih + 5505024;
        float* H_all   = embeds + 1376256;
        float* mean_f  = H_all + 1376256;
        float* h       = mean_f + 262144;
        float* c       = h + 65536;
        float* hp_g    = c + 65536;
        float* uwsplit = hp_g + 327680;
        float* biascat = uwsplit + 1310720;
        float* bsum    = biascat + 2560;
        float* sbuf    = bsum + 2048;

        u16* UWhi = (u16*)uwsplit;
        u16* UWlo = UWhi + (size_t)UWN * DDIM;
        u16* Thi = (u16*)embeds;
        u16* Tlo = Thi + (size_t)DDIM * EDIM;

        launch_split(stream, ih_w, EDIM, EDIM, DDIM, DDIM, Thi, Tlo);
        hipLaunchKernelGGL(mean_feat_kernel, dim3(BATCH * EDIM / 256), dim3(256), 0, stream,
                           features, mean_f);
        hipLaunchKernelGGL(small_mfma_gemm, dim3(DDIM / 8), dim3(256), 0, stream,
                           mean_f, EDIM, Thi, Tlo, EDIM, ih_b, h, DDIM);
        launch_split(stream, ic_w, EDIM, EDIM, DDIM, DDIM, Thi, Tlo);
        hipLaunchKernelGGL(small_mfma_gemm, dim3(DDIM / 8), dim3(256), 0, stream,
                           mean_f, EDIM, Thi, Tlo, EDIM, ic_b, c, DDIM);
        hipLaunchKernelGGL(gather_embed_kernel, dim3(BATCH * TT * EMBD / 256), dim3(256), 0, stream,
                           captions, embedding, embeds);
        hipLaunchKernelGGL(bias_sum_kernel, dim3((G4 + 255) / 256), dim3(256), 0, stream,
                           b_ih, b_hh, bsum);
        hipLaunchKernelGGL(uw_split_kernel, dim3((UWN * DDIM + 255) / 256), dim3(256), 0, stream,
                           Ua_w, Ua_b, W_hh, UWhi, UWlo, biascat);

        launch_gemm_mfma(stream, features, EDIM, Wa_w, EDIM, f_proj, DDIM, Wa_b,
                         BATCH * NF, DDIM, EDIM);
        launch_gemm_mfma(stream, features, EDIM, W_ih, EDIM + EMBD, F_ih, G4, nullptr,
                         BATCH * NF, G4, EDIM);
        launch_gemm_mfma(stream, embeds, EMBD, W_ih + EDIM, EDIM + EMBD, E_ih, G4, bsum,
                         BATCH * TT, G4, EMBD);

        for (int t = 0; t < TT; ++t) {
            hipLaunchKernelGGL(small_mfma_gemm, dim3(UWN / 8), dim3(256), 0, stream,
                               h, DDIM, UWhi, UWlo, DDIM, biascat, hp_g, UWN);
            hipLaunchKernelGGL(score_softmax_kernel, dim3(BATCH), dim3(256), 0, stream,
                               f_proj, hp_g, Va_w, Va_b, sbuf, out_w, t);
            hipLaunchKernelGGL(gates_lstm_kernel, dim3(BATCH * 4), dim3(128), 0, stream,
                               sbuf, hp_g, E_ih, F_ih, h, c, H_all, t);
        }

        launch_gemm_mfma(stream, H_all, DDIM, fc_w, DDIM, out_p, VOC, fc_b,
                         BATCH * TT, VOC, DDIM);
    }
}